// Round 1
// baseline (631.126 us; speedup 1.0000x reference)
//
#include <hip/hip_runtime.h>
#include <hip/hip_bf16.h>
#include <cstdint>

// Encoder_Decoder: C=80 classes, H=128, N=sum(lengths)=20640, L_max=416.
// Phases (all dense GEMMs f16 MFMA, fp32 accumulate):
//  1) concat extras (f16) into allf16[:,128:224]
//  2) allf16[:,:128] = relu(acbf @ appear_W^T + ab)      MFMA K=1024
//  3) dec16 = relu(allf16 @ feat_W^T + fb)               MFMA K=224
//  4) xp16[d][start+t] = dec16[gather] @ Wih^T + bih     MFMA K=128, per class
//  5) GRU scan per (class,dir): 128 thr x 3 rows, f16 weights + v_dot2.
//     xp staged global->LDS in 32-step double-buffered chunks (latency off
//     the serial chain); 16 hp frags loaded up-front; 6 accumulator chains.
//  6) out[n] = sigmoid(dot(outY[n,:256], out_W) + out_b)

typedef _Float16 half2_t __attribute__((ext_vector_type(2)));
typedef _Float16 half8_t __attribute__((ext_vector_type(8)));
typedef float f32x4 __attribute__((ext_vector_type(4)));

// LDS-only barrier: __syncthreads() drains vmcnt (in-flight global ops);
// cross-thread data here flows only through LDS, lgkmcnt(0) suffices.
__device__ __forceinline__ void lds_barrier() {
    asm volatile("s_waitcnt lgkmcnt(0)\n\ts_barrier" ::: "memory");
}

__device__ __forceinline__ void gload_lds16(const _Float16* g, _Float16* l) {
    __builtin_amdgcn_global_load_lds(
        (const __attribute__((address_space(1))) void*)g,
        (__attribute__((address_space(3))) void*)l, 16, 0, 0);
}

__device__ __forceinline__ half8_t cvt8(float4 f0, float4 f1) {
    return half8_t{(_Float16)f0.x, (_Float16)f0.y, (_Float16)f0.z, (_Float16)f0.w,
                   (_Float16)f1.x, (_Float16)f1.y, (_Float16)f1.z, (_Float16)f1.w};
}

// ---------------- 1. concat extras (f16) ----------------
__global__ __launch_bounds__(256) void concat_kernel(
    const float* __restrict__ score, const float* __restrict__ box,
    const float* __restrict__ orig, _Float16* __restrict__ allf, int N)
{
    int idx = blockIdx.x * 256 + threadIdx.x;
    int total = N * 96;
    if (idx >= total) return;
    int n = idx / 96, j = idx - n * 96;
    float v;
    if (j < 32)      v = score[(size_t)n * 32 + j];
    else if (j < 64) v = box  [(size_t)n * 32 + j - 32];
    else             v = orig [(size_t)n * 32 + j - 64];
    allf[(size_t)n * 224 + 128 + j] = (_Float16)v;
}

// ---------------- MFMA GEMM: C(N x 128) = act(A(N x K) @ B(128 x K)^T + bias) ----------------
// 256 thr = 4 waves; tile 64 rows x 128 cols; wave = 1 row-tile(16) x 8 col-tiles.
// K-chunk 32. LDS staged in MFMA fragment order (lane-contiguous 16B slots):
//   A slot u = rt*64 + q*16 + m  <- A[n0+rt*16+m][kc*32 + q*8 .. +7]
//   B slot u = ct*64 + q*16 + n  <- B[ct*16+n]  [kc*32 + q*8 .. +7]
// Frag layouts (m89-verified): A/B lane = idx&15 + 16*(k/8); C/D col=lane&15,
// row = 4*(lane>>4) + reg.
template<bool A_F16>
__global__ __launch_bounds__(256) void mfma_gemm_kernel(
    const void* __restrict__ Av, int lda,
    const float* __restrict__ B, int ldb,       // 128 x ldb f32 (ldb >= K)
    const float* __restrict__ bias,
    _Float16* __restrict__ Cc, int ldc,
    int Nrows, int K, int do_relu)
{
    __shared__ __align__(16) _Float16 Asl[256 * 8];   // 4 KB
    __shared__ __align__(16) _Float16 Bsl[512 * 8];   // 8 KB
    const int tid = threadIdx.x;
    const int wave = tid >> 6, lane = tid & 63;
    const int n0 = blockIdx.x * 64;

    // A staging: slot = tid
    const int a_rt = tid >> 6, a_q = (tid >> 4) & 3, a_m = tid & 15;
    int arow = n0 + a_rt * 16 + a_m; if (arow > Nrows - 1) arow = Nrows - 1;
    // B staging: slots tid and tid+256
    const int b_q = (tid >> 4) & 3, b_n = tid & 15;
    const int bcol0 = (tid >> 6) * 16 + b_n;          // ct 0..3
    const int bcol1 = bcol0 + 64;                     // ct 4..7

    f32x4 acc[8] = {};
    half8_t a_st, b_st0, b_st1;

    auto load_chunk = [&](int kc) {
        int k = kc * 32;
        if constexpr (A_F16) {
            const _Float16* A = (const _Float16*)Av;
            a_st = *(const half8_t*)(A + (size_t)arow * lda + k + a_q * 8);
        } else {
            const float* A = (const float*)Av;
            const float4* p = (const float4*)(A + (size_t)arow * lda + k + a_q * 8);
            a_st = cvt8(p[0], p[1]);
        }
        const float4* p0 = (const float4*)(B + (size_t)bcol0 * ldb + k + b_q * 8);
        const float4* p1 = (const float4*)(B + (size_t)bcol1 * ldb + k + b_q * 8);
        b_st0 = cvt8(p0[0], p0[1]);
        b_st1 = cvt8(p1[0], p1[1]);
    };

    load_chunk(0);
    const int nkc = K >> 5;
    for (int kc = 0; kc < nkc; kc++) {
        lds_barrier();                       // prev compute's LDS reads done
        *(half8_t*)(Asl + tid * 8) = a_st;
        *(half8_t*)(Bsl + tid * 8) = b_st0;
        *(half8_t*)(Bsl + (tid + 256) * 8) = b_st1;
        lds_barrier();
        if (kc + 1 < nkc) load_chunk(kc + 1);   // prefetch under MFMA
        half8_t af = *(const half8_t*)(Asl + (wave * 64 + lane) * 8);
        #pragma unroll
        for (int ct = 0; ct < 8; ct++) {
            half8_t bf = *(const half8_t*)(Bsl + (ct * 64 + lane) * 8);
            acc[ct] = __builtin_amdgcn_mfma_f32_16x16x32_f16(af, bf, acc[ct], 0, 0, 0);
        }
    }

    const int crow = n0 + wave * 16 + (lane >> 4) * 4;
    const int ccol = lane & 15;
    #pragma unroll
    for (int ct = 0; ct < 8; ct++) {
        int col = ct * 16 + ccol;
        float bv = bias[col];
        #pragma unroll
        for (int reg = 0; reg < 4; reg++) {
            int row = crow + reg;
            if (row >= Nrows) continue;
            float v = acc[ct][reg] + bv;
            if (do_relu) v = v > 0.f ? v : 0.f;
            Cc[(size_t)row * ldc + col] = (_Float16)v;
        }
    }
}

// ---------------- 4. Xp per-class MFMA GEMM (K=128) with direction gather ----------------
__global__ __launch_bounds__(256) void mfma_xp_kernel(
    const _Float16* __restrict__ dec, // N x 128 f16
    const float* __restrict__ Wih,    // C x 2 x 384 x 128 f32
    const float* __restrict__ bih,    // C x 2 x 384 f32
    const int* __restrict__ ucl,
    _Float16* __restrict__ xp,        // 2 x N x 384 f16
    int N)
{
    const int c = blockIdx.x;
    const int tile = blockIdx.y;
    const int d = blockIdx.z / 3, mt = blockIdx.z % 3;
    const int start = ucl[c];
    const int len = ucl[c + 1] - start;
    const int t0 = tile * 64;
    if (t0 >= len) return;

    __shared__ __align__(16) _Float16 Asl[256 * 8];
    __shared__ __align__(16) _Float16 Bsl[512 * 8];
    const int tid = threadIdx.x;
    const int wave = tid >> 6, lane = tid & 63;

    const int a_rt = tid >> 6, a_q = (tid >> 4) & 3, a_m = tid & 15;
    int t = t0 + a_rt * 16 + a_m; if (t > len - 1) t = len - 1;
    const int srow = start + (d ? (len - 1 - t) : t);

    const float* Bb = Wih + ((size_t)(c * 2 + d) * 384 + mt * 128) * 128;
    const int b_q = (tid >> 4) & 3, b_n = tid & 15;
    const int bcol0 = (tid >> 6) * 16 + b_n;
    const int bcol1 = bcol0 + 64;

    f32x4 acc[8] = {};
    half8_t a_st, b_st0, b_st1;

    auto load_chunk = [&](int kc) {
        int k = kc * 32;
        a_st = *(const half8_t*)(dec + (size_t)srow * 128 + k + a_q * 8);
        const float4* p0 = (const float4*)(Bb + (size_t)bcol0 * 128 + k + b_q * 8);
        const float4* p1 = (const float4*)(Bb + (size_t)bcol1 * 128 + k + b_q * 8);
        b_st0 = cvt8(p0[0], p0[1]);
        b_st1 = cvt8(p1[0], p1[1]);
    };

    load_chunk(0);
    for (int kc = 0; kc < 4; kc++) {
        lds_barrier();
        *(half8_t*)(Asl + tid * 8) = a_st;
        *(half8_t*)(Bsl + tid * 8) = b_st0;
        *(half8_t*)(Bsl + (tid + 256) * 8) = b_st1;
        lds_barrier();
        if (kc + 1 < 4) load_chunk(kc + 1);
        half8_t af = *(const half8_t*)(Asl + (wave * 64 + lane) * 8);
        #pragma unroll
        for (int ct = 0; ct < 8; ct++) {
            half8_t bf = *(const half8_t*)(Bsl + (ct * 64 + lane) * 8);
            acc[ct] = __builtin_amdgcn_mfma_f32_16x16x32_f16(af, bf, acc[ct], 0, 0, 0);
        }
    }

    const float* bias = bih + (size_t)(c * 2 + d) * 384 + mt * 128;
    const int trow = t0 + wave * 16 + (lane >> 4) * 4;
    const int ccol = lane & 15;
    #pragma unroll
    for (int ct = 0; ct < 8; ct++) {
        int col = ct * 16 + ccol;
        float bv = bias[col];
        #pragma unroll
        for (int reg = 0; reg < 4; reg++) {
            int tt = trow + reg;
            if (tt >= len) continue;
            float v = acc[ct][reg] + bv;
            xp[((size_t)d * N + start + tt) * 384 + mt * 128 + col] = (_Float16)v;
        }
    }
}

// ---------------- 5. GRU scan ----------------
// One block per (class,dir), 128 threads; thread g owns gate rows {g,g+128,g+256}.
// f16 weights in 192 VGPRs, v_dot2 matvec, f16 h via 512B LDS double-buffer,
// lgkmcnt-only barrier.
// v2: xp staged into LDS in 32-step chunks via global_load_lds (double-buffered,
// issued 32 substeps ahead -> HBM latency off the serial chain); all 16 hp
// fragments loaded up-front; 6 accumulator chains (K split in halves).
#define XCH 32
__global__ __launch_bounds__(128, 1) void gru_kernel(
    const _Float16* __restrict__ xp,  // 2 x N x 384 f16
    const float* __restrict__ Whh,    // C x 2 x 384 x 128
    const float* __restrict__ bhh,    // C x 2 x 384
    const int* __restrict__ ucl,
    float* __restrict__ outY,         // N x 256 f32
    int N)
{
    const int c = blockIdx.x, d = blockIdx.y;
    const int start = ucl[c];
    const int len = ucl[c + 1] - start;
    const int g = threadIdx.x;        // 0..127
    const int wave = g >> 6, lane = g & 63;

    __shared__ __align__(16) _Float16 xs[2][XCH * 384];   // 2 x 24 KB
    __shared__ __align__(16) half2_t hbuf[2][64];         // 512 B

    const _Float16* xpb = xp + ((size_t)d * N + start) * 384;
    const int slice = len * 384;      // halves in this (c,d) slice

    // Stage chunk ch (steps [ch*32, ch*32+32)) into xs[ch&1]:
    // 12288 halves = 24 KB = 24 wave-instrs of 1 KB (64 lanes x 16 B); 12/wave.
    // Global addr per-lane (clamped to slice end, stays 16B-aligned); LDS dest
    // is wave-uniform base + lane*16 (global_load_lds hardware layout).
    auto stage_chunk = [&](int ch) {
        const int base = ch * (XCH * 384);
        _Float16* lb = (_Float16*)xs[ch & 1];
        #pragma unroll
        for (int i = 0; i < 12; i++) {
            const int slot = wave * 12 + i;               // 0..23
            int off = base + slot * 512 + lane * 8;
            const int mx = slice - 8;
            if (off > mx) off = mx;                       // clamp, keeps 16B align
            gload_lds16(xpb + off, lb + slot * 512);
        }
    };

    stage_chunk(0);                   // in flight under the W-load phase

    const float* wbase = Whh + (size_t)(c * 2 + d) * 384 * 128;
    half2_t w0[64], w1[64], w2[64];
    {
        const float2* r0 = (const float2*)(wbase + (size_t)g * 128);
        const float2* r1 = (const float2*)(wbase + (size_t)(g + 128) * 128);
        const float2* r2 = (const float2*)(wbase + (size_t)(g + 256) * 128);
        #pragma unroll
        for (int i = 0; i < 64; i++) {
            float2 a = r0[i];
            w0[i] = half2_t{(_Float16)a.x, (_Float16)a.y};
        }
        #pragma unroll
        for (int i = 0; i < 64; i++) {
            float2 a = r1[i];
            w1[i] = half2_t{(_Float16)a.x, (_Float16)a.y};
        }
        #pragma unroll
        for (int i = 0; i < 64; i++) {
            float2 a = r2[i];
            w2[i] = half2_t{(_Float16)a.x, (_Float16)a.y};
        }
    }
    const float* bb = bhh + (size_t)(c * 2 + d) * 384;
    const float bh0 = bb[g], bh1 = bb[g + 128], bh2 = bb[g + 256];

    if (g < 64) { hbuf[0][g] = half2_t{(_Float16)0.f, (_Float16)0.f}; }
    float hcur = 0.f;
    float* outb = outY + (size_t)start * 256 + d * 128;

    // chunk 0 staged + h init visible to both waves
    asm volatile("s_waitcnt vmcnt(0) lgkmcnt(0)\n\ts_barrier" ::: "memory");

    const int nch = (len + XCH - 1) / XCH;
    if (nch > 1) stage_chunk(1);

    int t = 0;
    for (int ch = 0; ch < nch; ch++) {
        const _Float16* xc = (const _Float16*)xs[ch & 1];
        const int rem = len - ch * XCH;
        const int tend = rem < XCH ? rem : XCH;
        for (int tm = 0; tm < tend; tm++, t++) {
            // x from LDS (issued first; covered by the dot loop)
            float x0 = (float)xc[tm * 384 + g];
            float x1 = (float)xc[tm * 384 + 128 + g];
            float x2 = (float)xc[tm * 384 + 256 + g];
            // all 16 h fragments up-front (uniform-address broadcast reads)
            const half8_t* __restrict__ hp = (const half8_t*)hbuf[t & 1];
            half8_t h8[16];
            #pragma unroll
            for (int i = 0; i < 16; i++) h8[i] = hp[i];
            // 6 accumulator chains: gates x K-halves, reuse distance 12 cyc
            float a0 = bh0, a1 = bh1, a2 = bh2;
            float b0 = 0.f, b1 = 0.f, b2 = 0.f;
            #pragma unroll
            for (int i = 0; i < 8; i++) {
                union { half8_t v; half2_t h2[4]; } u, v2;
                u.v = h8[i]; v2.v = h8[i + 8];
                #pragma unroll
                for (int j = 0; j < 4; j++) {
                    a0 = __builtin_amdgcn_fdot2(w0[i * 4 + j],      u.h2[j],  a0, false);
                    b0 = __builtin_amdgcn_fdot2(w0[32 + i * 4 + j], v2.h2[j], b0, false);
                    a1 = __builtin_amdgcn_fdot2(w1[i * 4 + j],      u.h2[j],  a1, false);
                    b1 = __builtin_amdgcn_fdot2(w1[32 + i * 4 + j], v2.h2[j], b1, false);
                    a2 = __builtin_amdgcn_fdot2(w2[i * 4 + j],      u.h2[j],  a2, false);
                    b2 = __builtin_amdgcn_fdot2(w2[32 + i * 4 + j], v2.h2[j], b2, false);
                }
            }
            a0 += b0; a1 += b1; a2 += b2;
            float r = __fdividef(1.f, 1.f + __expf(-(x0 + a0)));
            float z = __fdividef(1.f, 1.f + __expf(-(x1 + a1)));
            float pre = x2 + r * a2;
            float n = 1.f - __fdividef(2.f, __expf(2.f * pre) + 1.f);
            float hnew = (1.f - z) * n + z * hcur;
            ((_Float16*)hbuf[(t + 1) & 1])[g] = (_Float16)hnew;
            hcur = hnew;
            int tt = d ? (len - 1 - t) : t;
            outb[(size_t)tt * 256 + g] = hnew;
            lds_barrier();
        }
        if (ch + 1 < nch) {
            // next chunk's staging must have landed (each wave waits its own
            // loads, then cross-wave barrier); then refill the buffer chunk
            // ch just finished with chunk ch+2 (32 substeps of cover).
            asm volatile("s_waitcnt vmcnt(0)" ::: "memory");
            __builtin_amdgcn_s_barrier();
            if (ch + 2 < nch) stage_chunk(ch + 2);
        }
    }
}
#undef XCH

// ---------------- 6. head: sigmoid(dot(outY[n], out_W) + b) ----------------
__global__ __launch_bounds__(256) void final_kernel(
    const float* __restrict__ outY,   // N x 256
    const float* __restrict__ outW,   // 256
    const float* __restrict__ outb,   // 1
    float* __restrict__ out, int N)
{
    __shared__ __align__(16) float wsh[256];
    wsh[threadIdx.x] = outW[threadIdx.x];
    __syncthreads();
    const int lane = threadIdx.x & 63;
    const int wave = (blockIdx.x * 256 + threadIdx.x) >> 6;
    const int nw = gridDim.x * 4;
    float4 w4 = *(const float4*)&wsh[lane * 4];
    float b = outb[0];
    for (int n = wave; n < N; n += nw) {
        float4 y = *(const float4*)(outY + (size_t)n * 256 + lane * 4);
        float p = y.x * w4.x + y.y * w4.y + y.z * w4.z + y.w * w4.w;
        #pragma unroll
        for (int off = 32; off > 0; off >>= 1) p += __shfl_down(p, off);
        if (lane == 0) out[n] = 1.f / (1.f + __expf(-(p + b)));
    }
}

extern "C" void kernel_launch(void* const* d_in, const int* in_sizes, int n_in,
                              void* d_out, int out_size, void* d_ws, size_t ws_size,
                              hipStream_t stream)
{
    const float* acbf  = (const float*)d_in[3];
    const float* score = (const float*)d_in[4];
    const float* box   = (const float*)d_in[5];
    const float* orig  = (const float*)d_in[6];
    const int*   ucl   = (const int*)d_in[8];
    const float* aW  = (const float*)d_in[9];
    const float* ab  = (const float*)d_in[10];
    const float* fW  = (const float*)d_in[11];
    const float* fb  = (const float*)d_in[12];
    const float* Wih = (const float*)d_in[13];
    const float* Whh = (const float*)d_in[14];
    const float* bih = (const float*)d_in[15];
    const float* bhh = (const float*)d_in[16];
    const float* oW  = (const float*)d_in[17];
    const float* ob  = (const float*)d_in[18];
    float* out = (float*)d_out;

    const int N = in_sizes[3] / 1024;   // 20640
    const int C = in_sizes[7];          // 80

    // workspace: allf16 N*224 | dec16 N*128 | xp16 2*N*384 | outY f32 N*256  (~67 MB)
    _Float16* allf16 = (_Float16*)d_ws;
    _Float16* dec16  = allf16 + (size_t)N * 224;
    _Float16* xp16   = dec16 + (size_t)N * 128;
    float*    outY   = (float*)(xp16 + (size_t)2 * N * 384);

    dim3 blk(256);
    const int rowblocks = (N + 63) / 64;
    concat_kernel<<<dim3((N * 96 + 255) / 256), blk, 0, stream>>>(score, box, orig, allf16, N);
    mfma_gemm_kernel<false><<<dim3(rowblocks), blk, 0, stream>>>(
        (const void*)acbf, 1024, aW, 1024, ab, allf16, 224, N, 1024, 1);
    mfma_gemm_kernel<true><<<dim3(rowblocks), blk, 0, stream>>>(
        (const void*)allf16, 224, fW, 224, fb, dec16, 128, N, 224, 1);
    mfma_xp_kernel<<<dim3(C, 7, 6), blk, 0, stream>>>(dec16, Wih, bih, ucl, xp16, N);
    gru_kernel<<<dim3(C, 2), dim3(128), 0, stream>>>(xp16, Whh, bhh, ucl, outY, N);
    final_kernel<<<dim3(160), blk, 0, stream>>>(outY, oW, ob, out, N);
}